// Round 7
// baseline (196.222 us; speedup 1.0000x reference)
//
#include <hip/hip_runtime.h>

#define G_N    32
#define MUL    128
#define RADII  20
#define CH     4
#define RES_B  180
#define RES_A  359
#define IDIM   36
#define COEFF_N (G_N*CH*RADII*IDIM)   // 92160 = 360*256
#define PER_G   (RADII*RES_B*RES_A)   // 1292400 floats per graph
#define PER_G4  (PER_G/4)             // 323100
#define NCHUNK 12
#define BCH    15                     // 180/12 betas per block

typedef float v2f __attribute__((ext_vector_type(2)));

__device__ __forceinline__ float fexp2(float x){
#if __has_builtin(__builtin_amdgcn_exp2f)
  return __builtin_amdgcn_exp2f(x);     // raw v_exp_f32 (base-2), args bounded
#else
  return exp2f(x);
#endif
}
__device__ __forceinline__ float flog2(float x){
#if __has_builtin(__builtin_amdgcn_logf)
  return __builtin_amdgcn_logf(x);      // raw v_log_f32 (base-2)
#else
  return log2f(x);
#endif
}
// monotone float<->uint mapping for atomicMax on signed floats
__device__ __forceinline__ unsigned enc_f(float f){
  unsigned u = __float_as_uint(f);
  return (u & 0x80000000u) ? ~u : (u | 0x80000000u);
}
__device__ __forceinline__ float dec_f(unsigned k){
  return __uint_as_float((k & 0x80000000u) ? (k ^ 0x80000000u) : ~k);
}

// Blocks 0..359: position_coeffs. Block 360: table setup (Gauss-Legendre nodes,
// normalized Legendre * log2e -> PYs; Fourier rows -> Ftab). The two are
// independent; fusing removes the serial one-CU setup dispatch.
__global__ __launch_bounds__(256) void fused_prep_kernel(
                              const float* __restrict__ focus, const float* __restrict__ embt,
                              const float* __restrict__ W, const int* __restrict__ tspec,
                              float* __restrict__ out,
                              float* __restrict__ PYs, float* __restrict__ Ftab){
  __shared__ double ak[RES_B + 1], bk[RES_B + 1];
  int blk = blockIdx.x;
  int t   = threadIdx.x;
  if (blk == 360){
    const double PI = 3.14159265358979323846;
    const double LOG2E = 1.4426950408889634074;
    if (t >= 2 && t <= RES_B){
      ak[t] = (2.0*t - 1.0) / (double)t;
      bk[t] = (t - 1.0) / (double)t;
    }
    __syncthreads();
    if (t < RES_B){
      int i = RES_B - 1 - t;                     // numpy leggauss: ascending nodes
      double x = cos(PI * (i + 0.75) / (RES_B + 0.5));
      for (int it = 0; it < 5; ++it){            // Newton on P_180
        double p0 = 1.0, p1 = x;
        for (int k = 2; k <= RES_B; ++k){
          double t1 = ak[k] * x;
          double pk = fma(t1, p1, -(bk[k] * p0));
          p0 = p1; p1 = pk;
        }
        x -= p1 * (x*x - 1.0) / ((double)RES_B * (x*p1 - p0));
      }
      double y = x;
      double sy = sqrt(fmax(1.0 - y*y, 0.0));
      double P[6][6];
      P[0][0] = 1.0;
      for (int m = 1; m < 6; ++m) P[m][m] = (2.0*m - 1.0)*sy*P[m-1][m-1];
      for (int m = 0; m < 5; ++m) P[m+1][m] = (2.0*m + 1.0)*y*P[m][m];
      for (int m = 0; m < 6; ++m)
        for (int l = m + 2; l < 6; ++l)
          P[l][m] = ((2.0*l - 1.0)*y*P[l-1][m] - (l + m - 1.0)*P[l-2][m]) / (double)(l - m);
      const double fact[11] = {1,1,2,6,24,120,720,5040,40320,362880,3628800};
      for (int l = 0; l < 6; ++l)
        for (int m = 0; m <= l; ++m){
          double K = sqrt((2.0*l + 1.0)/(4.0*PI)*fact[l-m]/fact[l+m]);
          double v = K * P[l][m] * LOG2E;
          if (m > 0) v *= sqrt(2.0);
          PYs[t*36 + l*6 + m] = (float)v;
        }
    }
    for (int a = t; a < RES_A; a += 256){
      double al = 2.0*PI*a/(double)RES_A;
      Ftab[a*12 + 0] = 1.0f;
      for (int m = 1; m <= 5; ++m){
        Ftab[a*12 + m]     = (float)cos(m*al);
        Ftab[a*12 + 5 + m] = (float)sin(m*al);
      }
      Ftab[a*12 + 11] = 0.f;
    }
  } else {
    int idx = blk * 256 + t;        // < 92160 always (360*256 exact)
    int i36 = idx % IDIM;
    int go  = idx / IDIM;           // g*80 + o, o = c*RADII + r
    int o   = go % (CH*RADII);
    int g   = go / (CH*RADII);
    int l   = (int)sqrtf((float)i36 + 0.5f);
    int mo  = i36 - l*l;            // m + l
    int dim = 2*l + 1;
    const float* fp = focus + g*(MUL*IDIM) + MUL*l*l + mo;
    const float* ep = embt + tspec[g]*(MUL*6) + MUL*l;
    const float* wp = W + l*(MUL*80) + o;
    float s = 0.f;
    #pragma unroll 4
    for (int i = 0; i < MUL; ++i)
      s = fmaf(fp[i*dim] * ep[i], wp[i*80], s);
    out[idx] = s * 0.088388347648318447f;  // 1/sqrt(128)
  }
}

// One block = (g, r, 15-beta chunk), 64 threads = ONE wave; 7680 blocks total
// (~16 resident/CU with the launch-bounds VGPR cap -> 4 waves/SIMD, vs 2.5 in
// the 45-beta version that was latency-bound).
// Phase 1: Legendre-contract tmpa[b][mm][c] into LDS (channel-minor).
// Phase 2: per beta, each lane reads the 44 uniform floats ONCE into VGPRs
// (11x ds_read_b128) and reuses them for THREE alpha-pairs p = tid+64k.
// h = C +/- S via packed f32. Stores sp = sum_c 2^h (exp-domain, unnormalized);
// per-graph max on sp (log monotone). fixup applies log2*ln2 minus graph max.
__global__ __launch_bounds__(64, 4) void compute_kernel(const float* __restrict__ coeffs,
                          const float* __restrict__ PYs, const float* __restrict__ Ftab,
                          float* __restrict__ out, unsigned* __restrict__ gmax){
  int blk   = blockIdx.x;
  int chunk = blk % NCHUNK;
  int gr    = blk / NCHUNK;                // g*RADII + r
  int r = gr % RADII;
  int g = gr / RADII;
  int tid = threadIdx.x;
  int b0  = chunk * BCH;

  __shared__ float cv[CH][IDIM];
  __shared__ __align__(16) float tmpa[BCH][12][4];   // [beta][mm][channel]

  for (int v = tid; v < CH*IDIM; v += 64){
    int c = v / IDIM, i = v % IDIM;
    cv[c][i] = coeffs[((g*CH + c)*RADII + r)*IDIM + i];
  }
  // 3 Fourier rows per lane: alpha = tid, tid+64, tid+128 (rows < 192 <= 358)
  float f0[11], f1[11], f2[11];
  {
    const float4* Fq = reinterpret_cast<const float4*>(Ftab);
    float4 a0 = Fq[tid*3],       a1 = Fq[tid*3+1],       a2 = Fq[tid*3+2];
    float4 b0v = Fq[(tid+64)*3], b1 = Fq[(tid+64)*3+1],  b2 = Fq[(tid+64)*3+2];
    float4 c0 = Fq[(tid+128)*3], c1 = Fq[(tid+128)*3+1], c2 = Fq[(tid+128)*3+2];
    f0[0]=a0.x; f0[1]=a0.y; f0[2]=a0.z; f0[3]=a0.w; f0[4]=a1.x; f0[5]=a1.y;
    f0[6]=a1.z; f0[7]=a1.w; f0[8]=a2.x; f0[9]=a2.y; f0[10]=a2.z;
    f1[0]=b0v.x; f1[1]=b0v.y; f1[2]=b0v.z; f1[3]=b0v.w; f1[4]=b1.x; f1[5]=b1.y;
    f1[6]=b1.z; f1[7]=b1.w; f1[8]=b2.x; f1[9]=b2.y; f1[10]=b2.z;
    f2[0]=c0.x; f2[1]=c0.y; f2[2]=c0.z; f2[3]=c0.w; f2[4]=c1.x; f2[5]=c1.y;
    f2[6]=c1.z; f2[7]=c1.w; f2[8]=c2.x; f2[9]=c2.y; f2[10]=c2.z;
  }
  __syncthreads();

  // phase 1: tmpa[b][mm][c] = sum_l cv[c][l^2+l+/-m] * PYs[b][l][|m|]
  for (int v = tid; v < BCH*44; v += 64){
    int bl = v / 44, cm = v % 44;
    int c = cm / 11, mm = cm % 11;
    int am, ii;
    if (mm == 0)      { am = 0;      ii = 0;        }
    else if (mm <= 5) { am = mm;     ii = mm;       }   // cos part: m > 0
    else              { am = mm - 5; ii = -(mm-5);  }   // sin part: m < 0
    const float* py = PYs + (b0 + bl)*36 + am;
    float s = 0.f;
    for (int l = am; l < 6; ++l)
      s = fmaf(cv[c][l*l + l + ii], py[l*6], s);
    tmpa[bl][mm][c] = s;
  }
  __syncthreads();

  float smax = 0.f;
  float* row = out + ((size_t)gr*RES_B + b0)*RES_A;
  for (int bl = 0; bl < BCH; ++bl){
    const float4* tq = reinterpret_cast<const float4*>(&tmpa[bl][0][0]);
    float4 q[11];
    #pragma unroll
    for (int mm = 0; mm < 11; ++mm) q[mm] = tq[mm];   // 11x ds_read_b128, once per beta
    #pragma unroll
    for (int k = 0; k < 3; ++k){
      if (k == 2 && tid >= 52) break;                  // p = tid+128 >= 180
      const float* fr = (k == 0) ? f0 : (k == 1) ? f1 : f2;
      int p = tid + 64*k;
      v2f C01 = {q[0].x, q[0].y}, C23 = {q[0].z, q[0].w};   // fr[0]==1
      #pragma unroll
      for (int mm = 1; mm <= 5; ++mm){
        v2f fs = {fr[mm], fr[mm]};
        C01 = __builtin_elementwise_fma((v2f){q[mm].x, q[mm].y}, fs, C01);
        C23 = __builtin_elementwise_fma((v2f){q[mm].z, q[mm].w}, fs, C23);
      }
      v2f f6 = {fr[6], fr[6]};
      v2f S01 = (v2f){q[6].x, q[6].y} * f6, S23 = (v2f){q[6].z, q[6].w} * f6;
      #pragma unroll
      for (int mm = 7; mm <= 10; ++mm){
        v2f fs = {fr[mm], fr[mm]};
        S01 = __builtin_elementwise_fma((v2f){q[mm].x, q[mm].y}, fs, S01);
        S23 = __builtin_elementwise_fma((v2f){q[mm].z, q[mm].w}, fs, S23);
      }
      v2f hp01 = C01 + S01, hp23 = C23 + S23;
      v2f hm01 = C01 - S01, hm23 = C23 - S23;
      float sp = (fexp2(hp01.x) + fexp2(hp01.y)) + (fexp2(hp23.x) + fexp2(hp23.y));
      float sm = (fexp2(hm01.x) + fexp2(hm01.y)) + (fexp2(hm23.x) + fexp2(hm23.y));
      row[p] = sp;
      if (p) row[359 - p] = sm;              // p==0: no mirror
      smax = fmaxf(smax, fmaxf(sp, sm));
    }
    row += RES_A;
  }
  #pragma unroll
  for (int off = 32; off > 0; off >>= 1)
    smax = fmaxf(smax, __shfl_xor(smax, off, 64));
  if (tid == 0)
    atomicMax(gmax + g, enc_f(smax));        // max of sp (exp-domain)
}

// BW-bound fix-up: logits[i] = ln2*(log2(sp) - log2(spmax_g)). Trans pipe is
// idle in a streaming kernel, so the logs are free here. float4 grid-stride.
__global__ __launch_bounds__(256) void fixup_kernel(float* __restrict__ logits,
                                                    const unsigned* __restrict__ gmax){
  const float LN2 = 0.69314718055994531f;
  const int total4 = G_N * PER_G4;
  float4* l4 = reinterpret_cast<float4*>(logits);
  int stride = gridDim.x * 256;
  for (int i = blockIdx.x * 256 + threadIdx.x; i < total4; i += stride){
    int g = (int)(((unsigned)i) / PER_G4);   // compile-time divisor -> magic mul
    float nsub = -flog2(dec_f(gmax[g])) * LN2;
    float4 v = l4[i];
    v.x = fmaf(flog2(v.x), LN2, nsub);
    v.y = fmaf(flog2(v.y), LN2, nsub);
    v.z = fmaf(flog2(v.z), LN2, nsub);
    v.w = fmaf(flog2(v.w), LN2, nsub);
    l4[i] = v;
  }
}

extern "C" void kernel_launch(void* const* d_in, const int* in_sizes, int n_in,
                              void* d_out, int out_size, void* d_ws, size_t ws_size,
                              hipStream_t stream){
  const float* focus = (const float*)d_in[0];
  const float* embt  = (const float*)d_in[1];
  const float* W     = (const float*)d_in[2];
  const int*   tspec = (const int*)d_in[3];
  float* out = (float*)d_out;
  float* ws  = (float*)d_ws;
  unsigned* gmax = (unsigned*)d_ws;          // 32 slots (128 B)
  float* PYs  = ws + 32;                     // [180][36]
  float* Ftab = ws + 32 + RES_B*36;          // [359][12], 16B-aligned

  hipMemsetAsync(d_ws, 0, 128, stream);      // enc(sp>0) > 0, so 0 is identity
  fused_prep_kernel<<<361, 256, 0, stream>>>(focus, embt, W, tspec, out, PYs, Ftab);
  float* logits = out + COEFF_N;
  compute_kernel<<<G_N*RADII*NCHUNK, 64, 0, stream>>>(out, PYs, Ftab, logits, gmax);
  fixup_kernel<<<2048, 256, 0, stream>>>(logits, gmax);
}

// Round 8
// 156.775 us; speedup vs baseline: 1.2516x; 1.2516x over previous
//
#include <hip/hip_runtime.h>

#define G_N    32
#define MUL    128
#define RADII  20
#define CH     4
#define RES_B  180
#define RES_A  359
#define IDIM   36
#define COEFF_N (G_N*CH*RADII*IDIM)   // 92160 = 360*256
#define PER_G   (RADII*RES_B*RES_A)   // 1292400 floats per graph
#define PER_G4  (PER_G/4)             // 323100
#define NCHUNK 3
#define BCH_BLK 60                    // betas per block (4 waves)
#define BCH_W   15                    // betas per wave

typedef float v2f __attribute__((ext_vector_type(2)));

__device__ __forceinline__ float fexp2(float x){
#if __has_builtin(__builtin_amdgcn_exp2f)
  return __builtin_amdgcn_exp2f(x);     // raw v_exp_f32 (base-2), args bounded
#else
  return exp2f(x);
#endif
}
__device__ __forceinline__ float flog2(float x){
#if __has_builtin(__builtin_amdgcn_logf)
  return __builtin_amdgcn_logf(x);      // raw v_log_f32 (base-2)
#else
  return log2f(x);
#endif
}
// monotone float<->uint mapping for atomicMax on signed floats
__device__ __forceinline__ unsigned enc_f(float f){
  unsigned u = __float_as_uint(f);
  return (u & 0x80000000u) ? ~u : (u | 0x80000000u);
}
__device__ __forceinline__ float dec_f(unsigned k){
  return __uint_as_float((k & 0x80000000u) ? (k ^ 0x80000000u) : ~k);
}

// Blocks 0..359: position_coeffs. Block 360: table setup (Gauss-Legendre nodes,
// normalized Legendre * log2e -> PYs; Fourier rows -> Ftab).
__global__ __launch_bounds__(256) void fused_prep_kernel(
                              const float* __restrict__ focus, const float* __restrict__ embt,
                              const float* __restrict__ W, const int* __restrict__ tspec,
                              float* __restrict__ out,
                              float* __restrict__ PYs, float* __restrict__ Ftab){
  __shared__ double ak[RES_B + 1], bk[RES_B + 1];
  int blk = blockIdx.x;
  int t   = threadIdx.x;
  if (blk == 360){
    const double PI = 3.14159265358979323846;
    const double LOG2E = 1.4426950408889634074;
    if (t >= 2 && t <= RES_B){
      ak[t] = (2.0*t - 1.0) / (double)t;
      bk[t] = (t - 1.0) / (double)t;
    }
    __syncthreads();
    if (t < RES_B){
      int i = RES_B - 1 - t;                     // numpy leggauss: ascending nodes
      double x = cos(PI * (i + 0.75) / (RES_B + 0.5));
      for (int it = 0; it < 5; ++it){            // Newton on P_180
        double p0 = 1.0, p1 = x;
        for (int k = 2; k <= RES_B; ++k){
          double t1 = ak[k] * x;
          double pk = fma(t1, p1, -(bk[k] * p0));
          p0 = p1; p1 = pk;
        }
        x -= p1 * (x*x - 1.0) / ((double)RES_B * (x*p1 - p0));
      }
      double y = x;
      double sy = sqrt(fmax(1.0 - y*y, 0.0));
      double P[6][6];
      P[0][0] = 1.0;
      for (int m = 1; m < 6; ++m) P[m][m] = (2.0*m - 1.0)*sy*P[m-1][m-1];
      for (int m = 0; m < 5; ++m) P[m+1][m] = (2.0*m + 1.0)*y*P[m][m];
      for (int m = 0; m < 6; ++m)
        for (int l = m + 2; l < 6; ++l)
          P[l][m] = ((2.0*l - 1.0)*y*P[l-1][m] - (l + m - 1.0)*P[l-2][m]) / (double)(l - m);
      const double fact[11] = {1,1,2,6,24,120,720,5040,40320,362880,3628800};
      for (int l = 0; l < 6; ++l)
        for (int m = 0; m <= l; ++m){
          double K = sqrt((2.0*l + 1.0)/(4.0*PI)*fact[l-m]/fact[l+m]);
          double v = K * P[l][m] * LOG2E;
          if (m > 0) v *= sqrt(2.0);
          PYs[t*36 + l*6 + m] = (float)v;
        }
    }
    for (int a = t; a < RES_A; a += 256){
      double al = 2.0*PI*a/(double)RES_A;
      Ftab[a*12 + 0] = 1.0f;
      for (int m = 1; m <= 5; ++m){
        Ftab[a*12 + m]     = (float)cos(m*al);
        Ftab[a*12 + 5 + m] = (float)sin(m*al);
      }
      Ftab[a*12 + 11] = 0.f;
    }
  } else {
    int idx = blk * 256 + t;        // < 92160 always (360*256 exact)
    int i36 = idx % IDIM;
    int go  = idx / IDIM;           // g*80 + o, o = c*RADII + r
    int o   = go % (CH*RADII);
    int g   = go / (CH*RADII);
    int l   = (int)sqrtf((float)i36 + 0.5f);
    int mo  = i36 - l*l;            // m + l
    int dim = 2*l + 1;
    const float* fp = focus + g*(MUL*IDIM) + MUL*l*l + mo;
    const float* ep = embt + tspec[g]*(MUL*6) + MUL*l;
    const float* wp = W + l*(MUL*80) + o;
    float s = 0.f;
    #pragma unroll 4
    for (int i = 0; i < MUL; ++i)
      s = fmaf(fp[i*dim] * ep[i], wp[i*80], s);
    out[idx] = s * 0.088388347648318447f;  // 1/sqrt(128)
  }
}

// One block = (g, r, 60-beta chunk), 256 threads = 4 waves (dodges the 1-wave
// workgroup-slot occupancy cap seen in R7: 31% occ, latency-bound).
// Phase 1: Legendre-contract tmpa[60][mm][c] into LDS cooperatively.
// Phase 2: wave w privately handles betas [w*15,w*15+15); per beta each lane
// reads the 44 uniform floats ONCE (11x ds_read_b128 broadcast) and reuses
// them for THREE alpha-pairs p = lane+64k. h = C +/- S via packed f32.
// Stores sp = sum_c 2^h (exp-domain, unnormalized); per-graph max on sp
// (log monotone). fixup applies log2*ln2 minus graph max.
__global__ __launch_bounds__(256, 4) void compute_kernel(const float* __restrict__ coeffs,
                          const float* __restrict__ PYs, const float* __restrict__ Ftab,
                          float* __restrict__ out, unsigned* __restrict__ gmax){
  int blk   = blockIdx.x;
  int chunk = blk % NCHUNK;
  int gr    = blk / NCHUNK;                // g*RADII + r
  int r = gr % RADII;
  int g = gr / RADII;
  int tid  = threadIdx.x;
  int wave = tid >> 6, lane = tid & 63;
  int b0   = chunk * BCH_BLK;              // block beta base

  __shared__ float cv[CH][IDIM];
  __shared__ __align__(16) float tmpa[BCH_BLK][12][4];   // [beta][mm][channel]
  __shared__ float wred[4];

  for (int v = tid; v < CH*IDIM; v += 256){
    int c = v / IDIM, i = v % IDIM;
    cv[c][i] = coeffs[((g*CH + c)*RADII + r)*IDIM + i];
  }
  // 3 Fourier rows per lane: alpha = lane, lane+64, lane+128 (rows < 192 <= 358)
  float f0[11], f1[11], f2[11];
  {
    const float4* Fq = reinterpret_cast<const float4*>(Ftab);
    float4 a0 = Fq[lane*3],       a1 = Fq[lane*3+1],       a2 = Fq[lane*3+2];
    float4 b0v = Fq[(lane+64)*3], b1 = Fq[(lane+64)*3+1],  b2 = Fq[(lane+64)*3+2];
    float4 c0 = Fq[(lane+128)*3], c1 = Fq[(lane+128)*3+1], c2 = Fq[(lane+128)*3+2];
    f0[0]=a0.x; f0[1]=a0.y; f0[2]=a0.z; f0[3]=a0.w; f0[4]=a1.x; f0[5]=a1.y;
    f0[6]=a1.z; f0[7]=a1.w; f0[8]=a2.x; f0[9]=a2.y; f0[10]=a2.z;
    f1[0]=b0v.x; f1[1]=b0v.y; f1[2]=b0v.z; f1[3]=b0v.w; f1[4]=b1.x; f1[5]=b1.y;
    f1[6]=b1.z; f1[7]=b1.w; f1[8]=b2.x; f1[9]=b2.y; f1[10]=b2.z;
    f2[0]=c0.x; f2[1]=c0.y; f2[2]=c0.z; f2[3]=c0.w; f2[4]=c1.x; f2[5]=c1.y;
    f2[6]=c1.z; f2[7]=c1.w; f2[8]=c2.x; f2[9]=c2.y; f2[10]=c2.z;
  }
  __syncthreads();

  // phase 1: tmpa[b][mm][c] = sum_l cv[c][l^2+l+/-m] * PYs[b][l][|m|]
  for (int v = tid; v < BCH_BLK*44; v += 256){
    int bl = v / 44, cm = v % 44;
    int c = cm / 11, mm = cm % 11;
    int am, ii;
    if (mm == 0)      { am = 0;      ii = 0;        }
    else if (mm <= 5) { am = mm;     ii = mm;       }   // cos part: m > 0
    else              { am = mm - 5; ii = -(mm-5);  }   // sin part: m < 0
    const float* py = PYs + (b0 + bl)*36 + am;
    float s = 0.f;
    for (int l = am; l < 6; ++l)
      s = fmaf(cv[c][l*l + l + ii], py[l*6], s);
    tmpa[bl][mm][c] = s;
  }
  __syncthreads();

  float smax = 0.f;
  float* row = out + ((size_t)gr*RES_B + b0 + wave*BCH_W)*RES_A;
  for (int bl = 0; bl < BCH_W; ++bl){
    const float4* tq = reinterpret_cast<const float4*>(&tmpa[wave*BCH_W + bl][0][0]);
    float4 q[11];
    #pragma unroll
    for (int mm = 0; mm < 11; ++mm) q[mm] = tq[mm];   // 11x ds_read_b128, once per beta
    #pragma unroll
    for (int k = 0; k < 3; ++k){
      if (k == 2 && lane >= 52) break;                 // p = lane+128 >= 180
      const float* fr = (k == 0) ? f0 : (k == 1) ? f1 : f2;
      int p = lane + 64*k;
      v2f C01 = {q[0].x, q[0].y}, C23 = {q[0].z, q[0].w};   // fr[0]==1
      #pragma unroll
      for (int mm = 1; mm <= 5; ++mm){
        v2f fs = {fr[mm], fr[mm]};
        C01 = __builtin_elementwise_fma((v2f){q[mm].x, q[mm].y}, fs, C01);
        C23 = __builtin_elementwise_fma((v2f){q[mm].z, q[mm].w}, fs, C23);
      }
      v2f f6 = {fr[6], fr[6]};
      v2f S01 = (v2f){q[6].x, q[6].y} * f6, S23 = (v2f){q[6].z, q[6].w} * f6;
      #pragma unroll
      for (int mm = 7; mm <= 10; ++mm){
        v2f fs = {fr[mm], fr[mm]};
        S01 = __builtin_elementwise_fma((v2f){q[mm].x, q[mm].y}, fs, S01);
        S23 = __builtin_elementwise_fma((v2f){q[mm].z, q[mm].w}, fs, S23);
      }
      v2f hp01 = C01 + S01, hp23 = C23 + S23;
      v2f hm01 = C01 - S01, hm23 = C23 - S23;
      float sp = (fexp2(hp01.x) + fexp2(hp01.y)) + (fexp2(hp23.x) + fexp2(hp23.y));
      float sm = (fexp2(hm01.x) + fexp2(hm01.y)) + (fexp2(hm23.x) + fexp2(hm23.y));
      row[p] = sp;
      if (p) row[359 - p] = sm;              // p==0: no mirror
      smax = fmaxf(smax, fmaxf(sp, sm));
    }
    row += RES_A;
  }
  #pragma unroll
  for (int off = 32; off > 0; off >>= 1)
    smax = fmaxf(smax, __shfl_xor(smax, off, 64));
  if (lane == 0) wred[wave] = smax;
  __syncthreads();
  if (tid == 0){
    float m = fmaxf(fmaxf(wred[0], wred[1]), fmaxf(wred[2], wred[3]));
    atomicMax(gmax + g, enc_f(m));           // max of sp (exp-domain)
  }
}

// BW-bound fix-up: logits[i] = ln2*(log2(sp) - log2(spmax_g)). Trans pipe is
// idle in a streaming kernel, so the logs are free here. float4 grid-stride.
__global__ __launch_bounds__(256) void fixup_kernel(float* __restrict__ logits,
                                                    const unsigned* __restrict__ gmax){
  const float LN2 = 0.69314718055994531f;
  const int total4 = G_N * PER_G4;
  float4* l4 = reinterpret_cast<float4*>(logits);
  int stride = gridDim.x * 256;
  for (int i = blockIdx.x * 256 + threadIdx.x; i < total4; i += stride){
    int g = (int)(((unsigned)i) / PER_G4);   // compile-time divisor -> magic mul
    float nsub = -flog2(dec_f(gmax[g])) * LN2;
    float4 v = l4[i];
    v.x = fmaf(flog2(v.x), LN2, nsub);
    v.y = fmaf(flog2(v.y), LN2, nsub);
    v.z = fmaf(flog2(v.z), LN2, nsub);
    v.w = fmaf(flog2(v.w), LN2, nsub);
    l4[i] = v;
  }
}

extern "C" void kernel_launch(void* const* d_in, const int* in_sizes, int n_in,
                              void* d_out, int out_size, void* d_ws, size_t ws_size,
                              hipStream_t stream){
  const float* focus = (const float*)d_in[0];
  const float* embt  = (const float*)d_in[1];
  const float* W     = (const float*)d_in[2];
  const int*   tspec = (const int*)d_in[3];
  float* out = (float*)d_out;
  float* ws  = (float*)d_ws;
  unsigned* gmax = (unsigned*)d_ws;          // 32 slots (128 B)
  float* PYs  = ws + 32;                     // [180][36]
  float* Ftab = ws + 32 + RES_B*36;          // [359][12], 16B-aligned

  hipMemsetAsync(d_ws, 0, 128, stream);      // enc(sp>0) > 0, so 0 is identity
  fused_prep_kernel<<<361, 256, 0, stream>>>(focus, embt, W, tspec, out, PYs, Ftab);
  float* logits = out + COEFF_N;
  compute_kernel<<<G_N*RADII*NCHUNK, 256, 0, stream>>>(out, PYs, Ftab, logits, gmax);
  fixup_kernel<<<2048, 256, 0, stream>>>(logits, gmax);
}